// Round 1
// baseline (846.808 us; speedup 1.0000x reference)
//
#include <hip/hip_runtime.h>

#define NN 100000
#define NE 1600000

// ---------------- workspace layout (bytes) ----------------
// cnt      : N ints
// row_ptr  : N+1 ints
// cursor   : N ints
// blockSum : 128 ints
// inv_deg  : N floats
// ssrc     : E ints (edge sources sorted by dst)
// agg      : N*128 floats
// h        : N*128 floats
static const size_t OFF_CNT  = 0;
static const size_t OFF_RP   = OFF_CNT  + 400128;
static const size_t OFF_CUR  = OFF_RP   + 400128;
static const size_t OFF_BS   = OFF_CUR  + 400128;
static const size_t OFF_INVD = OFF_BS   + 512;
static const size_t OFF_SSRC = OFF_INVD + 400128;
static const size_t OFF_AGG  = OFF_SSRC + 6400256;
static const size_t OFF_H    = OFF_AGG  + (size_t)NN * 128 * 4;

__global__ void zero_i32(int* __restrict__ p, int n) {
    int i = blockIdx.x * blockDim.x + threadIdx.x;
    if (i < n) p[i] = 0;
}

__global__ void count_k(const int* __restrict__ dst, int* __restrict__ cnt, int ne) {
    int e = blockIdx.x * blockDim.x + threadIdx.x;
    if (e < ne) atomicAdd(&cnt[dst[e]], 1);
}

// exclusive scan within 1024-blocks; block totals to blockSum
__global__ void scan_blocks(const int* __restrict__ cnt, int* __restrict__ rp,
                            int* __restrict__ blockSum, int n) {
    __shared__ int s[1024];
    int t = threadIdx.x;
    int gid = blockIdx.x * 1024 + t;
    int v = (gid < n) ? cnt[gid] : 0;
    s[t] = v;
    __syncthreads();
    for (int off = 1; off < 1024; off <<= 1) {
        int x = (t >= off) ? s[t - off] : 0;
        __syncthreads();
        s[t] += x;
        __syncthreads();
    }
    if (gid < n) rp[gid] = s[t] - v;   // exclusive within block
    if (t == 1023) blockSum[blockIdx.x] = s[1023];
}

__global__ void scan_sums(int* __restrict__ blockSum, int nb) {
    __shared__ int s[128];
    int t = threadIdx.x;
    int v = (t < nb) ? blockSum[t] : 0;
    s[t] = v;
    __syncthreads();
    for (int off = 1; off < 128; off <<= 1) {
        int x = (t >= off) ? s[t - off] : 0;
        __syncthreads();
        s[t] += x;
        __syncthreads();
    }
    if (t < nb) blockSum[t] = s[t] - v; // exclusive block offsets
}

__global__ void scan_add(int* __restrict__ rp, const int* __restrict__ blockSum,
                         const int* __restrict__ cnt, int* __restrict__ cursor,
                         float* __restrict__ inv_deg, int n, int ne) {
    int gid = blockIdx.x * blockDim.x + threadIdx.x;
    if (gid < n) {
        int v = rp[gid] + blockSum[gid >> 10];
        rp[gid] = v;
        cursor[gid] = v;
        int d = cnt[gid];
        inv_deg[gid] = 1.0f / (float)(d > 1 ? d : 1);
    }
    if (gid == 0) rp[n] = ne;
}

__global__ void fill_csr(const int* __restrict__ src, const int* __restrict__ dst,
                         int* __restrict__ cursor, int* __restrict__ ssrc, int ne) {
    int e = blockIdx.x * blockDim.x + threadIdx.x;
    if (e < ne) {
        int d = dst[e];
        int p = atomicAdd(&cursor[d], 1);
        ssrc[p] = src[e];
    }
}

// one wave (64 lanes) per node; lane owns 2 of the 128 features
__global__ __launch_bounds__(256) void aggregate(const float* __restrict__ feat,
                                                 const int* __restrict__ rp,
                                                 const int* __restrict__ ssrc,
                                                 const float* __restrict__ inv_deg,
                                                 float* __restrict__ out, int n) {
    int wave = (blockIdx.x * blockDim.x + threadIdx.x) >> 6;
    int lane = threadIdx.x & 63;
    if (wave >= n) return;
    int beg = rp[wave], end = rp[wave + 1];
    float ax = 0.f, ay = 0.f;
    for (int e = beg; e < end; ++e) {
        int s = ssrc[e];
        float2 v = *(const float2*)&feat[(size_t)s * 128 + lane * 2];
        ax += v.x;
        ay += v.y;
    }
    float id = inv_deg[wave];
    float2 o = {ax * id, ay * id};
    *(float2*)&out[(size_t)wave * 128 + lane * 2] = o;
}

// out = relu(A @ Wl + X @ Wr + bias); 64 rows/block, thread = 8 rows x 4 cols
__global__ __launch_bounds__(256) void sage_gemm(const float* __restrict__ A,
                                                 const float* __restrict__ X,
                                                 const float* __restrict__ Wl,
                                                 const float* __restrict__ Wr,
                                                 const float* __restrict__ bias,
                                                 float* __restrict__ out, int n) {
    __shared__ float sW[128 * 128];
    const int t = threadIdx.x;
    const int cg = t & 31;            // col group: cols 4*cg..4*cg+3
    const int rg = t >> 5;            // row group: 8 rows
    const int rowBase = blockIdx.x * 64 + rg * 8;

    int roff[8];
#pragma unroll
    for (int i = 0; i < 8; ++i) {
        int r = rowBase + i;
        r = (r < n) ? r : (n - 1);
        roff[i] = r * 128;
    }

    float acc[8][4];
#pragma unroll
    for (int i = 0; i < 8; ++i)
#pragma unroll
        for (int j = 0; j < 4; ++j) acc[i][j] = 0.f;

    for (int phase = 0; phase < 2; ++phase) {
        const float* W = phase ? Wr : Wl;
        const float* M = phase ? X : A;
        __syncthreads();
        for (int i = t; i < 4096; i += 256)
            ((float4*)sW)[i] = ((const float4*)W)[i];
        __syncthreads();

        for (int k = 0; k < 128; k += 4) {
            float4 w0 = *(const float4*)&sW[(k + 0) * 128 + cg * 4];
            float4 w1 = *(const float4*)&sW[(k + 1) * 128 + cg * 4];
            float4 w2 = *(const float4*)&sW[(k + 2) * 128 + cg * 4];
            float4 w3 = *(const float4*)&sW[(k + 3) * 128 + cg * 4];
#pragma unroll
            for (int i = 0; i < 8; ++i) {
                float4 a = *(const float4*)&M[roff[i] + k];
                acc[i][0] += a.x * w0.x + a.y * w1.x + a.z * w2.x + a.w * w3.x;
                acc[i][1] += a.x * w0.y + a.y * w1.y + a.z * w2.y + a.w * w3.y;
                acc[i][2] += a.x * w0.z + a.y * w1.z + a.z * w2.z + a.w * w3.z;
                acc[i][3] += a.x * w0.w + a.y * w1.w + a.z * w2.w + a.w * w3.w;
            }
        }
    }

    float4 bv = *(const float4*)&bias[cg * 4];
#pragma unroll
    for (int i = 0; i < 8; ++i) {
        int r = rowBase + i;
        if (r < n) {
            float4 o;
            o.x = fmaxf(acc[i][0] + bv.x, 0.f);
            o.y = fmaxf(acc[i][1] + bv.y, 0.f);
            o.z = fmaxf(acc[i][2] + bv.z, 0.f);
            o.w = fmaxf(acc[i][3] + bv.w, 0.f);
            *(float4*)&out[(size_t)r * 128 + cg * 4] = o;
        }
    }
}

__global__ void final_linear(const float* __restrict__ H, const float* __restrict__ Wlin,
                             const float* __restrict__ blin, float* __restrict__ out, int n) {
    int r = blockIdx.x * blockDim.x + threadIdx.x;
    if (r >= n) return;
    float a0 = blin[0], a1 = blin[1];
    const float* hrow = H + (size_t)r * 128;
    for (int c = 0; c < 128; c += 2) {
        float2 hv = *(const float2*)&hrow[c];
        float4 wv = *(const float4*)&Wlin[c * 2];
        a0 += hv.x * wv.x + hv.y * wv.z;
        a1 += hv.x * wv.y + hv.y * wv.w;
    }
    float2 o = {a0, a1};
    *(float2*)&out[(size_t)r * 2] = o;
}

extern "C" void kernel_launch(void* const* d_in, const int* in_sizes, int n_in,
                              void* d_out, int out_size, void* d_ws, size_t ws_size,
                              hipStream_t stream) {
    const float* x    = (const float*)d_in[0];
    const int*   ei   = (const int*)d_in[1];
    const float* W1l  = (const float*)d_in[2];
    const float* b1   = (const float*)d_in[3];
    const float* W1r  = (const float*)d_in[4];
    const float* W2l  = (const float*)d_in[5];
    const float* b2   = (const float*)d_in[6];
    const float* W2r  = (const float*)d_in[7];
    const float* Wlin = (const float*)d_in[8];
    const float* blin = (const float*)d_in[9];
    float* out = (float*)d_out;

    char* ws = (char*)d_ws;
    int*   cnt     = (int*)(ws + OFF_CNT);
    int*   row_ptr = (int*)(ws + OFF_RP);
    int*   cursor  = (int*)(ws + OFF_CUR);
    int*   bsum    = (int*)(ws + OFF_BS);
    float* inv_deg = (float*)(ws + OFF_INVD);
    int*   ssrc    = (int*)(ws + OFF_SSRC);
    float* agg     = (float*)(ws + OFF_AGG);
    float* h       = (float*)(ws + OFF_H);

    const int* src = ei;        // edge_index[0]
    const int* dst = ei + NE;   // edge_index[1]

    // ---- CSR build ----
    zero_i32<<<(NN + 255) / 256, 256, 0, stream>>>(cnt, NN);
    count_k<<<(NE + 255) / 256, 256, 0, stream>>>(dst, cnt, NE);
    scan_blocks<<<(NN + 1023) / 1024, 1024, 0, stream>>>(cnt, row_ptr, bsum, NN);
    scan_sums<<<1, 128, 0, stream>>>(bsum, (NN + 1023) / 1024);
    scan_add<<<(NN + 255) / 256, 256, 0, stream>>>(row_ptr, bsum, cnt, cursor, inv_deg, NN, NE);
    fill_csr<<<(NE + 255) / 256, 256, 0, stream>>>(src, dst, cursor, ssrc, NE);

    // ---- layer 1 ----
    aggregate<<<(NN * 64 + 255) / 256, 256, 0, stream>>>(x, row_ptr, ssrc, inv_deg, agg, NN);
    sage_gemm<<<(NN + 63) / 64, 256, 0, stream>>>(agg, x, W1l, W1r, b1, h, NN);

    // ---- layer 2 ----
    aggregate<<<(NN * 64 + 255) / 256, 256, 0, stream>>>(h, row_ptr, ssrc, inv_deg, agg, NN);
    sage_gemm<<<(NN + 63) / 64, 256, 0, stream>>>(agg, h, W2l, W2r, b2, agg, NN);

    // ---- final linear ----
    final_linear<<<(NN + 255) / 256, 256, 0, stream>>>(agg, Wlin, blin, out, NN);
}

// Round 2
// 672.079 us; speedup vs baseline: 1.2600x; 1.2600x over previous
//
#include <hip/hip_runtime.h>

#define NN 100000
#define NE 1600000

typedef _Float16 f16x8 __attribute__((ext_vector_type(8)));
typedef float f32x4 __attribute__((ext_vector_type(4)));

// ---------------- workspace layout (bytes) ----------------
static const size_t OFF_CNT  = 0;                       // N ints
static const size_t OFF_RP   = OFF_CNT  + 400128;       // N+1 ints
static const size_t OFF_CUR  = OFF_RP   + 400128;       // N ints
static const size_t OFF_BS   = OFF_CUR  + 400128;       // 128 ints
static const size_t OFF_INVD = OFF_BS   + 512;          // N floats
static const size_t OFF_SSRC = OFF_INVD + 400128;       // E ints
static const size_t OFF_B1   = OFF_SSRC + 6400256;      // 128x256 f16
static const size_t OFF_B2   = OFF_B1   + 65536;
static const size_t OFF_X16  = OFF_B2   + 65536;        // N*128 f16 (x16; later reused as h2)
static const size_t OFF_H16  = OFF_X16  + 25600000;     // N*128 f16
static const size_t OFF_AGG  = OFF_H16  + 25600000;     // N*128 f16

static __device__ inline float h2f(uint bits) {
    return (float)__builtin_bit_cast(_Float16, (ushort)bits);
}
static __device__ inline ushort f2h(float f) {
    return __builtin_bit_cast(ushort, (_Float16)f);
}
static __device__ inline uint pk2h(float a, float b) {
    return (uint)f2h(a) | ((uint)f2h(b) << 16);
}

__global__ void zero_i32(int* __restrict__ p, int n) {
    int i = blockIdx.x * blockDim.x + threadIdx.x;
    if (i < n) p[i] = 0;
}

__global__ void count_k(const int* __restrict__ dst, int* __restrict__ cnt, int ne) {
    int e = blockIdx.x * blockDim.x + threadIdx.x;
    if (e < ne) atomicAdd(&cnt[dst[e]], 1);
}

__global__ void scan_blocks(const int* __restrict__ cnt, int* __restrict__ rp,
                            int* __restrict__ blockSum, int n) {
    __shared__ int s[1024];
    int t = threadIdx.x;
    int gid = blockIdx.x * 1024 + t;
    int v = (gid < n) ? cnt[gid] : 0;
    s[t] = v;
    __syncthreads();
    for (int off = 1; off < 1024; off <<= 1) {
        int x = (t >= off) ? s[t - off] : 0;
        __syncthreads();
        s[t] += x;
        __syncthreads();
    }
    if (gid < n) rp[gid] = s[t] - v;
    if (t == 1023) blockSum[blockIdx.x] = s[1023];
}

__global__ void scan_sums(int* __restrict__ blockSum, int nb) {
    __shared__ int s[128];
    int t = threadIdx.x;
    int v = (t < nb) ? blockSum[t] : 0;
    s[t] = v;
    __syncthreads();
    for (int off = 1; off < 128; off <<= 1) {
        int x = (t >= off) ? s[t - off] : 0;
        __syncthreads();
        s[t] += x;
        __syncthreads();
    }
    if (t < nb) blockSum[t] = s[t] - v;
}

__global__ void scan_add(int* __restrict__ rp, const int* __restrict__ blockSum,
                         const int* __restrict__ cnt, int* __restrict__ cursor,
                         float* __restrict__ inv_deg, int n, int ne) {
    int gid = blockIdx.x * blockDim.x + threadIdx.x;
    if (gid < n) {
        int v = rp[gid] + blockSum[gid >> 10];
        rp[gid] = v;
        cursor[gid] = v;
        int d = cnt[gid];
        inv_deg[gid] = 1.0f / (float)(d > 1 ? d : 1);
    }
    if (gid == 0) rp[n] = ne;
}

__global__ void fill_csr(const int* __restrict__ src, const int* __restrict__ dst,
                         int* __restrict__ cursor, int* __restrict__ ssrc, int ne) {
    int e = blockIdx.x * blockDim.x + threadIdx.x;
    if (e < ne) {
        int d = dst[e];
        int p = atomicAdd(&cursor[d], 1);
        ssrc[p] = src[e];
    }
}

// fp32 [n][128] -> f16 [n][128]
__global__ void to_f16(const float* __restrict__ in, ushort* __restrict__ out, int n4) {
    int i = blockIdx.x * blockDim.x + threadIdx.x;
    if (i < n4) {
        float4 v = ((const float4*)in)[i];
        uint2 o;
        o.x = pk2h(v.x, v.y);
        o.y = pk2h(v.z, v.w);
        ((uint2*)out)[i] = o;
    }
}

// pack [Wl;Wr] (each [128][128] fp32, row=k col=n) into Bt f16 [n][k'=256]
__global__ void prep_w(const float* __restrict__ Wl, const float* __restrict__ Wr,
                       ushort* __restrict__ Bt) {
    int id = blockIdx.x * blockDim.x + threadIdx.x;
    if (id >= 32768) return;
    int nw = id & 127;
    int km = id >> 7;               // m*128 + k
    const float* W = (km < 128) ? Wl : Wr;
    int k = km & 127;
    Bt[(size_t)nw * 256 + km] = f2h(W[k * 128 + nw]);
}

// one wave per node; lane owns features [2*lane, 2*lane+1]; f16 gather, fp32 accum
__global__ __launch_bounds__(256) void aggregate16(const ushort* __restrict__ feat,
                                                   const int* __restrict__ rp,
                                                   const int* __restrict__ ssrc,
                                                   const float* __restrict__ inv_deg,
                                                   ushort* __restrict__ outv, int n) {
    int wave = (blockIdx.x * blockDim.x + threadIdx.x) >> 6;
    int lane = threadIdx.x & 63;
    if (wave >= n) return;
    int beg = rp[wave], end = rp[wave + 1];
    float ax = 0.f, ay = 0.f;
    for (int e = beg; e < end; ++e) {
        int s = ssrc[e];
        uint v = *(const uint*)&feat[(size_t)s * 128 + lane * 2];
        ax += h2f(v & 0xffffu);
        ay += h2f(v >> 16);
    }
    float id = inv_deg[wave];
    *(uint*)&outv[(size_t)wave * 128 + lane * 2] = pk2h(ax * id, ay * id);
}

// relu(Aop@Wl + Xop@Wr + bias) in f16/MFMA; out f16 [n][128]
// block tile 128 rows x 128 cols, 4 waves (2x2 of 64x64), K'=256 in 4 chunks of 64
__global__ __launch_bounds__(256, 2) void sage_gemm_f16(const ushort* __restrict__ Aop,
                                                        const ushort* __restrict__ Xop,
                                                        const ushort* __restrict__ Bt,
                                                        const float* __restrict__ bias,
                                                        ushort* __restrict__ outH, int n) {
    __shared__ __align__(16) ushort sA[2][128 * 64];
    __shared__ __align__(16) ushort sB[2][128 * 64];
    const int t = threadIdx.x;
    const int l = t & 63;
    const int w = t >> 6;
    const int wr = (w >> 1) * 64, wc = (w & 1) * 64;
    const int rowBase = blockIdx.x * 128;
    const int sr = t >> 1, sh = t & 1;   // staging: row, 32-f16 half

    f32x4 acc[4][4];
#pragma unroll
    for (int i = 0; i < 4; ++i)
#pragma unroll
        for (int j = 0; j < 4; ++j) acc[i][j] = 0.0f;

    int4 rA[4], rB[4];
    int arow = rowBase + sr;
    if (arow >= n) arow = n - 1;

    auto gload = [&](int c) {
        const ushort* srcA = (c < 2) ? Aop : Xop;
        const int4* ga = (const int4*)(srcA + (size_t)arow * 128 + (c & 1) * 64 + sh * 32);
        const int4* gb = (const int4*)(Bt + (size_t)sr * 256 + c * 64 + sh * 32);
        rA[0] = ga[0]; rA[1] = ga[1]; rA[2] = ga[2]; rA[3] = ga[3];
        rB[0] = gb[0]; rB[1] = gb[1]; rB[2] = gb[2]; rB[3] = gb[3];
    };
    auto swrite = [&](int buf) {
        char* bA = (char*)&sA[buf][0] + sr * 128;
        char* bB = (char*)&sB[buf][0] + sr * 128;
        const int swz = (sr & 7) << 4;
        const int b0 = sh * 64;
        *(int4*)(bA + ((b0 +  0) ^ swz)) = rA[0];
        *(int4*)(bA + ((b0 + 16) ^ swz)) = rA[1];
        *(int4*)(bA + ((b0 + 32) ^ swz)) = rA[2];
        *(int4*)(bA + ((b0 + 48) ^ swz)) = rA[3];
        *(int4*)(bB + ((b0 +  0) ^ swz)) = rB[0];
        *(int4*)(bB + ((b0 + 16) ^ swz)) = rB[1];
        *(int4*)(bB + ((b0 + 32) ^ swz)) = rB[2];
        *(int4*)(bB + ((b0 + 48) ^ swz)) = rB[3];
    };

    gload(0);
    swrite(0);
    __syncthreads();

    for (int c = 0; c < 4; ++c) {
        const int buf = c & 1;
        if (c < 3) gload(c + 1);   // issue next-chunk loads early (hide HBM under MFMA)

#pragma unroll
        for (int ks = 0; ks < 2; ++ks) {
            f16x8 af[4], bf[4];
#pragma unroll
            for (int i = 0; i < 4; ++i) {
                int r = wr + i * 16 + (l & 15);
                af[i] = *(const f16x8*)((char*)&sA[buf][0] + r * 128 +
                                        ((ks * 64 + (l >> 4) * 16) ^ ((r & 7) << 4)));
                int cn = wc + i * 16 + (l & 15);
                bf[i] = *(const f16x8*)((char*)&sB[buf][0] + cn * 128 +
                                        ((ks * 64 + (l >> 4) * 16) ^ ((cn & 7) << 4)));
            }
#pragma unroll
            for (int i = 0; i < 4; ++i)
#pragma unroll
                for (int j = 0; j < 4; ++j)
                    acc[i][j] = __builtin_amdgcn_mfma_f32_16x16x32_f16(af[i], bf[j], acc[i][j], 0, 0, 0);
        }

        __syncthreads();
        if (c < 3) {
            swrite(buf ^ 1);
            __syncthreads();
        }
    }

    // epilogue: bias + relu, store f16
#pragma unroll
    for (int j = 0; j < 4; ++j) {
        int col = wc + j * 16 + (l & 15);
        float bb = bias[col];
#pragma unroll
        for (int i = 0; i < 4; ++i) {
#pragma unroll
            for (int q = 0; q < 4; ++q) {
                int row = rowBase + wr + i * 16 + (l >> 4) * 4 + q;
                if (row < n) {
                    float v = fmaxf(acc[i][j][q] + bb, 0.f);
                    outH[(size_t)row * 128 + col] = f2h(v);
                }
            }
        }
    }
}

__global__ void final_linear16(const ushort* __restrict__ H, const float* __restrict__ Wlin,
                               const float* __restrict__ blin, float* __restrict__ out, int n) {
    int r = blockIdx.x * blockDim.x + threadIdx.x;
    if (r >= n) return;
    float a0 = blin[0], a1 = blin[1];
    const ushort* hr = H + (size_t)r * 128;
    for (int c = 0; c < 128; c += 2) {
        uint v = *(const uint*)&hr[c];
        float h0 = h2f(v & 0xffffu);
        float h1 = h2f(v >> 16);
        float4 wv = *(const float4*)&Wlin[c * 2];
        a0 += h0 * wv.x + h1 * wv.z;
        a1 += h0 * wv.y + h1 * wv.w;
    }
    float2 o = {a0, a1};
    *(float2*)&out[(size_t)r * 2] = o;
}

extern "C" void kernel_launch(void* const* d_in, const int* in_sizes, int n_in,
                              void* d_out, int out_size, void* d_ws, size_t ws_size,
                              hipStream_t stream) {
    const float* x    = (const float*)d_in[0];
    const int*   ei   = (const int*)d_in[1];
    const float* W1l  = (const float*)d_in[2];
    const float* b1   = (const float*)d_in[3];
    const float* W1r  = (const float*)d_in[4];
    const float* W2l  = (const float*)d_in[5];
    const float* b2   = (const float*)d_in[6];
    const float* W2r  = (const float*)d_in[7];
    const float* Wlin = (const float*)d_in[8];
    const float* blin = (const float*)d_in[9];
    float* out = (float*)d_out;

    char* ws = (char*)d_ws;
    int*    cnt     = (int*)(ws + OFF_CNT);
    int*    row_ptr = (int*)(ws + OFF_RP);
    int*    cursor  = (int*)(ws + OFF_CUR);
    int*    bsum    = (int*)(ws + OFF_BS);
    float*  inv_deg = (float*)(ws + OFF_INVD);
    int*    ssrc    = (int*)(ws + OFF_SSRC);
    ushort* B1c     = (ushort*)(ws + OFF_B1);
    ushort* B2c     = (ushort*)(ws + OFF_B2);
    ushort* x16     = (ushort*)(ws + OFF_X16);
    ushort* h16     = (ushort*)(ws + OFF_H16);
    ushort* agg16   = (ushort*)(ws + OFF_AGG);

    const int* src = ei;
    const int* dst = ei + NE;

    // weight packing + feature f16 conversion
    prep_w<<<128, 256, 0, stream>>>(W1l, W1r, B1c);
    prep_w<<<128, 256, 0, stream>>>(W2l, W2r, B2c);
    to_f16<<<(NN * 32 + 255) / 256, 256, 0, stream>>>(x, x16, NN * 32);

    // CSR build
    zero_i32<<<(NN + 255) / 256, 256, 0, stream>>>(cnt, NN);
    count_k<<<(NE + 255) / 256, 256, 0, stream>>>(dst, cnt, NE);
    scan_blocks<<<(NN + 1023) / 1024, 1024, 0, stream>>>(cnt, row_ptr, bsum, NN);
    scan_sums<<<1, 128, 0, stream>>>(bsum, (NN + 1023) / 1024);
    scan_add<<<(NN + 255) / 256, 256, 0, stream>>>(row_ptr, bsum, cnt, cursor, inv_deg, NN, NE);
    fill_csr<<<(NE + 255) / 256, 256, 0, stream>>>(src, dst, cursor, ssrc, NE);

    // layer 1
    aggregate16<<<(NN * 64 + 255) / 256, 256, 0, stream>>>(x16, row_ptr, ssrc, inv_deg, agg16, NN);
    sage_gemm_f16<<<(NN + 127) / 128, 256, 0, stream>>>(agg16, x16, B1c, b1, h16, NN);

    // layer 2 (h2 goes into the dead x16 buffer)
    aggregate16<<<(NN * 64 + 255) / 256, 256, 0, stream>>>(h16, row_ptr, ssrc, inv_deg, agg16, NN);
    sage_gemm_f16<<<(NN + 127) / 128, 256, 0, stream>>>(agg16, h16, B2c, b2, x16, NN);

    // final linear
    final_linear16<<<(NN + 255) / 256, 256, 0, stream>>>(x16, Wlin, blin, out, NN);
}

// Round 3
// 484.984 us; speedup vs baseline: 1.7461x; 1.3858x over previous
//
#include <hip/hip_runtime.h>

#define NN 100000
#define NE 1600000
#define NEPAD 1900000   // NE + 3*NN upper bound for 4-padded CSR

typedef _Float16 f16x8 __attribute__((ext_vector_type(8)));
typedef float f32x4 __attribute__((ext_vector_type(4)));

// ---------------- workspace layout (bytes) ----------------
static const size_t OFF_CNT  = 0;                        // N ints
static const size_t OFF_RP   = OFF_CNT  + 400128;        // N+1 ints (padded offsets)
static const size_t OFF_CUR  = OFF_RP   + 400128;        // N ints
static const size_t OFF_BS   = OFF_CUR  + 400128;        // 128 ints
static const size_t OFF_INVD = OFF_BS   + 512;           // N floats
static const size_t OFF_SSRC = OFF_INVD + 400128;        // NEPAD ints
static const size_t OFF_B1   = OFF_SSRC + 7600000;       // 128x256 f16
static const size_t OFF_B2   = OFF_B1   + 65536;
static const size_t OFF_X16  = OFF_B2   + 65536;         // (N+1)*128 f16 (row N = zeros)
static const size_t OFF_H16  = OFF_X16  + 25600256;      // (N+1)*128 f16 (row N = zeros)
static const size_t OFF_AGG  = OFF_H16  + 25600256;      // N*128 f16

static __device__ inline float h2f(uint bits) {
    return (float)__builtin_bit_cast(_Float16, (ushort)bits);
}
static __device__ inline ushort f2h(float f) {
    return __builtin_bit_cast(ushort, (_Float16)f);
}
static __device__ inline uint pk2h(float a, float b) {
    return (uint)f2h(a) | ((uint)f2h(b) << 16);
}

__global__ void zero_i32(int* __restrict__ p, int n) {
    int i = blockIdx.x * blockDim.x + threadIdx.x;
    if (i < n) p[i] = 0;
}

// pre-fill padded CSR slots with the dummy zero-row index NN
__global__ void fill_pad(int* __restrict__ ssrc) {
    int i = blockIdx.x * blockDim.x + threadIdx.x;
    if (i < NEPAD) ssrc[i] = NN;
}

__global__ void zero_dummy(ushort* __restrict__ a, ushort* __restrict__ b) {
    int t = threadIdx.x;
    a[(size_t)NN * 128 + t] = 0;
    b[(size_t)NN * 128 + t] = 0;
}

__global__ void count_k(const int* __restrict__ dst, int* __restrict__ cnt, int ne) {
    int e = blockIdx.x * blockDim.x + threadIdx.x;
    if (e < ne) atomicAdd(&cnt[dst[e]], 1);
}

// exclusive scan of 4-padded counts within 1024-blocks
__global__ void scan_blocks(const int* __restrict__ cnt, int* __restrict__ rp,
                            int* __restrict__ blockSum, int n) {
    __shared__ int s[1024];
    int t = threadIdx.x;
    int gid = blockIdx.x * 1024 + t;
    int v = (gid < n) ? ((cnt[gid] + 3) & ~3) : 0;
    s[t] = v;
    __syncthreads();
    for (int off = 1; off < 1024; off <<= 1) {
        int x = (t >= off) ? s[t - off] : 0;
        __syncthreads();
        s[t] += x;
        __syncthreads();
    }
    if (gid < n) rp[gid] = s[t] - v;
    if (t == 1023) blockSum[blockIdx.x] = s[1023];
}

__global__ void scan_sums(int* __restrict__ blockSum, int nb) {
    __shared__ int s[128];
    int t = threadIdx.x;
    int v = (t < nb) ? blockSum[t] : 0;
    s[t] = v;
    __syncthreads();
    for (int off = 1; off < 128; off <<= 1) {
        int x = (t >= off) ? s[t - off] : 0;
        __syncthreads();
        s[t] += x;
        __syncthreads();
    }
    if (t < nb) blockSum[t] = s[t] - v;
}

__global__ void scan_add(int* __restrict__ rp, const int* __restrict__ blockSum,
                         const int* __restrict__ cnt, int* __restrict__ cursor,
                         float* __restrict__ inv_deg, int n) {
    int gid = blockIdx.x * blockDim.x + threadIdx.x;
    if (gid < n) {
        int v = rp[gid] + blockSum[gid >> 10];
        rp[gid] = v;
        cursor[gid] = v;
        int d = cnt[gid];
        inv_deg[gid] = 1.0f / (float)(d > 1 ? d : 1);
        if (gid == n - 1) rp[n] = v + ((d + 3) & ~3);
    }
}

__global__ void fill_csr(const int* __restrict__ src, const int* __restrict__ dst,
                         int* __restrict__ cursor, int* __restrict__ ssrc, int ne) {
    int e = blockIdx.x * blockDim.x + threadIdx.x;
    if (e < ne) {
        int d = dst[e];
        int p = atomicAdd(&cursor[d], 1);
        ssrc[p] = src[e];
    }
}

// fp32 [n][128] -> f16 [n][128]
__global__ void to_f16(const float* __restrict__ in, ushort* __restrict__ out, int n4) {
    int i = blockIdx.x * blockDim.x + threadIdx.x;
    if (i < n4) {
        float4 v = ((const float4*)in)[i];
        uint2 o;
        o.x = pk2h(v.x, v.y);
        o.y = pk2h(v.z, v.w);
        ((uint2*)out)[i] = o;
    }
}

// pack [Wl;Wr] into Bt f16 [n][k'=256]
__global__ void prep_w(const float* __restrict__ Wl, const float* __restrict__ Wr,
                       ushort* __restrict__ Bt) {
    int id = blockIdx.x * blockDim.x + threadIdx.x;
    if (id >= 32768) return;
    int nw = id & 127;
    int km = id >> 7;
    const float* W = (km < 128) ? Wl : Wr;
    int k = km & 127;
    Bt[(size_t)nw * 256 + km] = f2h(W[k * 128 + nw]);
}

// one wave per node; 4-edge groups with index prefetch; pad slots hit zero row NN
__global__ __launch_bounds__(256) void aggregate16(const ushort* __restrict__ feat,
                                                   const int* __restrict__ rp,
                                                   const int* __restrict__ ssrc,
                                                   const float* __restrict__ inv_deg,
                                                   ushort* __restrict__ outv, int n) {
    int wave = (blockIdx.x * blockDim.x + threadIdx.x) >> 6;
    int lane = threadIdx.x & 63;
    if (wave >= n) return;
    int beg = rp[wave], end = rp[wave + 1];
    const size_t loff = (size_t)(lane * 2);
    float a0 = 0.f, a1 = 0.f, b0 = 0.f, b1 = 0.f;
    int e = beg;
    if (e < end) {
        int4 s4 = *(const int4*)(ssrc + e);
        for (; e < end; e += 4) {
            int4 c = s4;
            int en = e + 4;
            int pn = (en < end) ? en : e;           // branchless prefetch addr
            s4 = *(const int4*)(ssrc + pn);
            uint v0 = *(const uint*)(feat + (size_t)c.x * 128 + loff);
            uint v1 = *(const uint*)(feat + (size_t)c.y * 128 + loff);
            uint v2 = *(const uint*)(feat + (size_t)c.z * 128 + loff);
            uint v3 = *(const uint*)(feat + (size_t)c.w * 128 + loff);
            a0 += h2f(v0 & 0xffffu); a1 += h2f(v0 >> 16);
            b0 += h2f(v1 & 0xffffu); b1 += h2f(v1 >> 16);
            a0 += h2f(v2 & 0xffffu); a1 += h2f(v2 >> 16);
            b0 += h2f(v3 & 0xffffu); b1 += h2f(v3 >> 16);
        }
    }
    float id = inv_deg[wave];
    *(uint*)&outv[(size_t)wave * 128 + loff] = pk2h((a0 + b0) * id, (a1 + b1) * id);
}

// relu(Aop@Wl + Xop@Wr + bias) via f16 MFMA; 128x128 tile, 4 waves, K'=256
__global__ __launch_bounds__(256, 2) void sage_gemm_f16(const ushort* __restrict__ Aop,
                                                        const ushort* __restrict__ Xop,
                                                        const ushort* __restrict__ Bt,
                                                        const float* __restrict__ bias,
                                                        ushort* __restrict__ outH, int n) {
    __shared__ __align__(16) ushort sA[2][128 * 64];
    __shared__ __align__(16) ushort sB[2][128 * 64];
    const int t = threadIdx.x;
    const int l = t & 63;
    const int w = t >> 6;
    const int wr = (w >> 1) * 64, wc = (w & 1) * 64;
    const int rowBase = blockIdx.x * 128;
    const int sr = t >> 1, sh = t & 1;

    f32x4 acc[4][4];
#pragma unroll
    for (int i = 0; i < 4; ++i)
#pragma unroll
        for (int j = 0; j < 4; ++j) acc[i][j] = 0.0f;

    int4 rA[4], rB[4];
    int arow = rowBase + sr;
    if (arow >= n) arow = n - 1;

    auto gload = [&](int c) {
        const ushort* srcA = (c < 2) ? Aop : Xop;
        const int4* ga = (const int4*)(srcA + (size_t)arow * 128 + (c & 1) * 64 + sh * 32);
        const int4* gb = (const int4*)(Bt + (size_t)sr * 256 + c * 64 + sh * 32);
        rA[0] = ga[0]; rA[1] = ga[1]; rA[2] = ga[2]; rA[3] = ga[3];
        rB[0] = gb[0]; rB[1] = gb[1]; rB[2] = gb[2]; rB[3] = gb[3];
    };
    auto swrite = [&](int buf) {
        char* bA = (char*)&sA[buf][0] + sr * 128;
        char* bB = (char*)&sB[buf][0] + sr * 128;
        const int swz = (sr & 7) << 4;
        const int b0 = sh * 64;
        *(int4*)(bA + ((b0 +  0) ^ swz)) = rA[0];
        *(int4*)(bA + ((b0 + 16) ^ swz)) = rA[1];
        *(int4*)(bA + ((b0 + 32) ^ swz)) = rA[2];
        *(int4*)(bA + ((b0 + 48) ^ swz)) = rA[3];
        *(int4*)(bB + ((b0 +  0) ^ swz)) = rB[0];
        *(int4*)(bB + ((b0 + 16) ^ swz)) = rB[1];
        *(int4*)(bB + ((b0 + 32) ^ swz)) = rB[2];
        *(int4*)(bB + ((b0 + 48) ^ swz)) = rB[3];
    };

    gload(0);
    swrite(0);
    __syncthreads();

    for (int c = 0; c < 4; ++c) {
        const int buf = c & 1;
        if (c < 3) gload(c + 1);

#pragma unroll
        for (int ks = 0; ks < 2; ++ks) {
            f16x8 af[4], bf[4];
#pragma unroll
            for (int i = 0; i < 4; ++i) {
                int r = wr + i * 16 + (l & 15);
                af[i] = *(const f16x8*)((char*)&sA[buf][0] + r * 128 +
                                        ((ks * 64 + (l >> 4) * 16) ^ ((r & 7) << 4)));
                int cn = wc + i * 16 + (l & 15);
                bf[i] = *(const f16x8*)((char*)&sB[buf][0] + cn * 128 +
                                        ((ks * 64 + (l >> 4) * 16) ^ ((cn & 7) << 4)));
            }
#pragma unroll
            for (int i = 0; i < 4; ++i)
#pragma unroll
                for (int j = 0; j < 4; ++j)
                    acc[i][j] = __builtin_amdgcn_mfma_f32_16x16x32_f16(af[i], bf[j], acc[i][j], 0, 0, 0);
        }

        __syncthreads();
        if (c < 3) {
            swrite(buf ^ 1);
            __syncthreads();
        }
    }

#pragma unroll
    for (int j = 0; j < 4; ++j) {
        int col = wc + j * 16 + (l & 15);
        float bb = bias[col];
#pragma unroll
        for (int i = 0; i < 4; ++i) {
#pragma unroll
            for (int q = 0; q < 4; ++q) {
                int row = rowBase + wr + i * 16 + (l >> 4) * 4 + q;
                if (row < n) {
                    float v = fmaxf(acc[i][j][q] + bb, 0.f);
                    outH[(size_t)row * 128 + col] = f2h(v);
                }
            }
        }
    }
}

__global__ void final_linear16(const ushort* __restrict__ H, const float* __restrict__ Wlin,
                               const float* __restrict__ blin, float* __restrict__ out, int n) {
    int r = blockIdx.x * blockDim.x + threadIdx.x;
    if (r >= n) return;
    float a0 = blin[0], a1 = blin[1];
    const ushort* hr = H + (size_t)r * 128;
    for (int c = 0; c < 128; c += 2) {
        uint v = *(const uint*)&hr[c];
        float h0 = h2f(v & 0xffffu);
        float h1 = h2f(v >> 16);
        float4 wv = *(const float4*)&Wlin[c * 2];
        a0 += h0 * wv.x + h1 * wv.z;
        a1 += h0 * wv.y + h1 * wv.w;
    }
    float2 o = {a0, a1};
    *(float2*)&out[(size_t)r * 2] = o;
}

extern "C" void kernel_launch(void* const* d_in, const int* in_sizes, int n_in,
                              void* d_out, int out_size, void* d_ws, size_t ws_size,
                              hipStream_t stream) {
    const float* x    = (const float*)d_in[0];
    const int*   ei   = (const int*)d_in[1];
    const float* W1l  = (const float*)d_in[2];
    const float* b1   = (const float*)d_in[3];
    const float* W1r  = (const float*)d_in[4];
    const float* W2l  = (const float*)d_in[5];
    const float* b2   = (const float*)d_in[6];
    const float* W2r  = (const float*)d_in[7];
    const float* Wlin = (const float*)d_in[8];
    const float* blin = (const float*)d_in[9];
    float* out = (float*)d_out;

    char* ws = (char*)d_ws;
    int*    cnt     = (int*)(ws + OFF_CNT);
    int*    row_ptr = (int*)(ws + OFF_RP);
    int*    cursor  = (int*)(ws + OFF_CUR);
    int*    bsum    = (int*)(ws + OFF_BS);
    float*  inv_deg = (float*)(ws + OFF_INVD);
    int*    ssrc    = (int*)(ws + OFF_SSRC);
    ushort* B1c     = (ushort*)(ws + OFF_B1);
    ushort* B2c     = (ushort*)(ws + OFF_B2);
    ushort* x16     = (ushort*)(ws + OFF_X16);
    ushort* h16     = (ushort*)(ws + OFF_H16);
    ushort* agg16   = (ushort*)(ws + OFF_AGG);

    const int* src = ei;
    const int* dst = ei + NE;

    // weight packing + f16 conversion + dummy zero rows
    prep_w<<<128, 256, 0, stream>>>(W1l, W1r, B1c);
    prep_w<<<128, 256, 0, stream>>>(W2l, W2r, B2c);
    to_f16<<<(NN * 32 + 255) / 256, 256, 0, stream>>>(x, x16, NN * 32);
    zero_dummy<<<1, 128, 0, stream>>>(x16, h16);

    // CSR build (4-padded segments, pad slots -> zero row NN)
    zero_i32<<<(NN + 255) / 256, 256, 0, stream>>>(cnt, NN);
    fill_pad<<<(NEPAD + 255) / 256, 256, 0, stream>>>(ssrc);
    count_k<<<(NE + 255) / 256, 256, 0, stream>>>(dst, cnt, NE);
    scan_blocks<<<(NN + 1023) / 1024, 1024, 0, stream>>>(cnt, row_ptr, bsum, NN);
    scan_sums<<<1, 128, 0, stream>>>(bsum, (NN + 1023) / 1024);
    scan_add<<<(NN + 255) / 256, 256, 0, stream>>>(row_ptr, bsum, cnt, cursor, inv_deg, NN);
    fill_csr<<<(NE + 255) / 256, 256, 0, stream>>>(src, dst, cursor, ssrc, NE);

    // layer 1
    aggregate16<<<(NN * 64 + 255) / 256, 256, 0, stream>>>(x16, row_ptr, ssrc, inv_deg, agg16, NN);
    sage_gemm_f16<<<(NN + 127) / 128, 256, 0, stream>>>(agg16, x16, B1c, b1, h16, NN);

    // layer 2 (h2 goes into the dead x16 buffer)
    aggregate16<<<(NN * 64 + 255) / 256, 256, 0, stream>>>(h16, row_ptr, ssrc, inv_deg, agg16, NN);
    sage_gemm_f16<<<(NN + 127) / 128, 256, 0, stream>>>(agg16, h16, B2c, b2, x16, NN);

    // final linear
    final_linear16<<<(NN + 255) / 256, 256, 0, stream>>>(x16, Wlin, blin, out, NN);
}